// Round 7
// baseline (6377.700 us; speedup 1.0000x reference)
//
#include <hip/hip_runtime.h>

typedef _Float16 h2 __attribute__((ext_vector_type(2)));
typedef _Float16 h8 __attribute__((ext_vector_type(8)));
typedef float f4 __attribute__((ext_vector_type(4)));

// ---------------- convert fp32 -> f16 ----------------
__global__ void cvt_f32_f16(const float* __restrict__ s, _Float16* __restrict__ d, int n) {
    int i = blockIdx.x * blockDim.x + threadIdx.x;
    if (i < n) d[i] = (_Float16)s[i];
}

// ---------------- combined GEMM bias: b_ih + b_hh for r,z cols; b_ih for n cols ----------------
__global__ void prep_bias(const float* __restrict__ bih, const float* __restrict__ bhh,
                          float* __restrict__ b2, int n) {
    int i = blockIdx.x * blockDim.x + threadIdx.x;
    if (i < n) {
        int c = i % 768;
        float v = bih[i];
        if (c < 512) v += bhh[i];
        b2[i] = v;
    }
}

// ---------------- x_proj GEMM: C[M][768] = A[M][256] * Bt[768][256]^T + bias ----------------
template<bool AF16>
__global__ __launch_bounds__(256, 2) void gemm_xproj(
    const void* __restrict__ Ap, const _Float16* __restrict__ Bt,
    const float* __restrict__ bias, float* __restrict__ C)
{
    __shared__ __align__(16) _Float16 As[128 * 40];
    __shared__ __align__(16) _Float16 Bs[128 * 40];
    const int tid = threadIdx.x;
    const size_t m0 = (size_t)blockIdx.x * 128;
    const int n0 = blockIdx.y * 128;
    const int lane = tid & 63, wave = tid >> 6;
    const int wm = wave >> 1, wn = wave & 1;
    const int r16 = lane & 15, kg = lane >> 4;
    f4 acc[4][4] = {};
    for (int k0 = 0; k0 < 256; k0 += 32) {
        if (k0) __syncthreads();
        #pragma unroll
        for (int u = 0; u < 2; ++u) {
            int c = tid + u * 256;
            int row = c >> 2, off = (c & 3) * 8;
            h8 av;
            if constexpr (AF16) {
                av = *(const h8*)((const _Float16*)Ap + (m0 + row) * 256 + k0 + off);
            } else {
                const float* ap = (const float*)Ap + (m0 + row) * 256 + k0 + off;
                f4 f0 = *(const f4*)ap, f1 = *(const f4*)(ap + 4);
                av[0]=(_Float16)f0[0]; av[1]=(_Float16)f0[1]; av[2]=(_Float16)f0[2]; av[3]=(_Float16)f0[3];
                av[4]=(_Float16)f1[0]; av[5]=(_Float16)f1[1]; av[6]=(_Float16)f1[2]; av[7]=(_Float16)f1[3];
            }
            *(h8*)&As[row * 40 + off] = av;
            h8 bv = *(const h8*)(Bt + (size_t)(n0 + row) * 256 + k0 + off);
            *(h8*)&Bs[row * 40 + off] = bv;
        }
        __syncthreads();
        h8 af[4], bf[4];
        #pragma unroll
        for (int mi = 0; mi < 4; ++mi) af[mi] = *(const h8*)&As[(wm*64 + mi*16 + r16) * 40 + kg * 8];
        #pragma unroll
        for (int ni = 0; ni < 4; ++ni) bf[ni] = *(const h8*)&Bs[(wn*64 + ni*16 + r16) * 40 + kg * 8];
        #pragma unroll
        for (int mi = 0; mi < 4; ++mi)
            #pragma unroll
            for (int ni = 0; ni < 4; ++ni)
                acc[mi][ni] = __builtin_amdgcn_mfma_f32_16x16x32_f16(af[mi], bf[ni], acc[mi][ni], 0, 0, 0);
    }
    #pragma unroll
    for (int mi = 0; mi < 4; ++mi)
        #pragma unroll
        for (int ni = 0; ni < 4; ++ni) {
            int col = n0 + wn*64 + ni*16 + r16;
            float bv = bias[col];
            #pragma unroll
            for (int r = 0; r < 4; ++r) {
                int row = wm*64 + mi*16 + kg*4 + r;
                C[(m0 + row) * 768 + col] = acc[mi][ni][r] + bv;
            }
        }
}

// ---------------- recurrent scan: MFMA with W_hh as B-fragments in AGPRs ----------------
// 512 thr = 8 waves, 2 waves/SIMD -> 256 regs/wave. Wave w owns cols [32w, 32w+32).
// B-frags: 3 gates x 2 N-tiles x 8 K-tiles x 4 regs = 192 AGPRs, read in-place by MFMA.
// A-frag (h) broadcast from LDS: all 16 A-rows identical -> every lane's D reg0 is
// the dot-product for its col (lane&15) -> gate math uniform across lanes, no shuffles.
template<bool OUTF32>
__global__
__attribute__((amdgpu_flat_work_group_size(512, 512), amdgpu_waves_per_eu(2, 2)))
void gru_scan_mfma(
    const float* __restrict__ xp,        // [B][T][768] fp32 (x_proj; b_ih + b_hh(r,z) folded)
    const _Float16* __restrict__ Whh,    // [768][256] f16
    const float* __restrict__ bhh,       // [768] (only n-part used)
    float* __restrict__ o32,             // layer 2 -> d_out
    _Float16* __restrict__ o16)          // layer 1 -> next GEMM input (f16)
{
    __shared__ __align__(16) _Float16 hh[2][256];
    const int b = blockIdx.x, tid = threadIdx.x;
    const int w = tid >> 6, lane = tid & 63;
    const int l15 = lane & 15, kg = lane >> 4;
    const int j0 = 32 * w;

    // ---- one-time B-frag load: Bf[g][nt][kk], lane l holds W[g*256+j0+nt*16+(l&15)][kk*32+kg*8 ..+8]
    h8 Bf[3][2][8];
    #pragma unroll
    for (int g = 0; g < 3; ++g)
        #pragma unroll
        for (int nt = 0; nt < 2; ++nt) {
            const _Float16* rp = Whh + (size_t)(g * 256 + j0 + nt * 16 + l15) * 256 + kg * 8;
            #pragma unroll
            for (int kk = 0; kk < 8; ++kk)
                Bf[g][nt][kk] = *(const h8*)(rp + kk * 32);
        }

    const float bn0 = bhh[512 + j0 + l15];
    const float bn1 = bhh[512 + j0 + 16 + l15];
    if (tid < 256) hh[0][tid] = (_Float16)1.0f;
    float hp0 = 1.0f, hp1 = 1.0f;      // fp32 h state for this lane's 2 cols (uniform across kg)
    __syncthreads();

    const float* xb = xp + (size_t)b * 2048 * 768;
    int xoff[6];                        // u = g*2+nt
    float c0[6], c1[6];
    #pragma unroll
    for (int u = 0; u < 6; ++u) {
        xoff[u] = (u >> 1) * 256 + j0 + (u & 1) * 16 + l15;
        c0[u] = xb[xoff[u]];
        c1[u] = xb[768 + xoff[u]];
    }

    int cur = 0;
    for (int t = 0; t < 2048; ++t) {
        // depth-2 x_proj prefetch
        const float* xnx = xb + (size_t)((t + 2 < 2048) ? t + 2 : 2047) * 768;
        float p2[6];
        #pragma unroll
        for (int u = 0; u < 6; ++u) p2[u] = xnx[xoff[u]];

        const _Float16* hc = hh[cur];
        f4 D[6] = {};                   // [g*2+nt]
        #pragma unroll
        for (int kk = 0; kk < 8; ++kk) {
            h8 A = *(const h8*)(hc + kk * 32 + kg * 8);   // 4-address broadcast read
            D[0] = __builtin_amdgcn_mfma_f32_16x16x32_f16(A, Bf[0][0][kk], D[0], 0, 0, 0);
            D[1] = __builtin_amdgcn_mfma_f32_16x16x32_f16(A, Bf[0][1][kk], D[1], 0, 0, 0);
            D[2] = __builtin_amdgcn_mfma_f32_16x16x32_f16(A, Bf[1][0][kk], D[2], 0, 0, 0);
            D[3] = __builtin_amdgcn_mfma_f32_16x16x32_f16(A, Bf[1][1][kk], D[3], 0, 0, 0);
            D[4] = __builtin_amdgcn_mfma_f32_16x16x32_f16(A, Bf[2][0][kk], D[4], 0, 0, 0);
            D[5] = __builtin_amdgcn_mfma_f32_16x16x32_f16(A, Bf[2][1][kk], D[5], 0, 0, 0);
        }

        // gates: D[u][0] valid on ALL lanes (identical A-rows) for col l15
        float rg0 = 1.f / (1.f + __expf(-(c0[0] + D[0][0])));
        float rg1 = 1.f / (1.f + __expf(-(c0[1] + D[1][0])));
        float zg0 = 1.f / (1.f + __expf(-(c0[2] + D[2][0])));
        float zg1 = 1.f / (1.f + __expf(-(c0[3] + D[3][0])));
        float na0 = c0[4] + rg0 * (D[4][0] + bn0);
        float na1 = c0[5] + rg1 * (D[5][0] + bn1);
        float e0 = __expf(-2.f * fabsf(na0));
        float e1 = __expf(-2.f * fabsf(na1));
        float ng0 = copysignf((1.f - e0) / (1.f + e0), na0);
        float ng1 = copysignf((1.f - e1) / (1.f + e1), na1);
        float hn0 = (1.f - zg0) * ng0 + zg0 * hp0;
        float hn1 = (1.f - zg1) * ng1 + zg1 * hp1;
        hp0 = hn0; hp1 = hn1;

        const int nxt = cur ^ 1;
        if (kg == 0) {                   // lanes 0-15 write
            hh[nxt][j0 + l15]      = (_Float16)hn0;
            hh[nxt][j0 + 16 + l15] = (_Float16)hn1;
            size_t oi = ((size_t)b * 2048 + t) * 256 + j0 + l15;
            if constexpr (OUTF32) { o32[oi] = hn0; o32[oi + 16] = hn1; }
            else                  { o16[oi] = (_Float16)hn0; o16[oi + 16] = (_Float16)hn1; }
        }
        __syncthreads();
        cur = nxt;
        #pragma unroll
        for (int u = 0; u < 6; ++u) { c0[u] = c1[u]; c1[u] = p2[u]; }
    }
}

// ---------------- launch ----------------
extern "C" void kernel_launch(void* const* d_in, const int* in_sizes, int n_in,
                              void* d_out, int out_size, void* d_ws, size_t ws_size,
                              hipStream_t stream) {
    const float* x    = (const float*)d_in[0];
    const float* W_ih = (const float*)d_in[1];
    const float* W_hh = (const float*)d_in[2];
    const float* b_ih = (const float*)d_in[3];
    const float* b_hh = (const float*)d_in[4];
    float* out = (float*)d_out;

    char* ws = (char*)d_ws;
    float*     xproj = (float*)ws;                                   // 201,326,592 B
    _Float16*  Wih_h = (_Float16*)(ws + 201326592);
    _Float16*  Whh_h = (_Float16*)(ws + 201326592 + 786432);
    _Float16*  y1h   = (_Float16*)(ws + 201326592 + 2 * 786432);     // 33,554,432 B
    float*     bias2 = (float*)(ws + 201326592 + 2 * 786432 + 33554432);  // 6,144 B

    cvt_f32_f16<<<1536, 256, 0, stream>>>(W_ih, Wih_h, 393216);
    cvt_f32_f16<<<1536, 256, 0, stream>>>(W_hh, Whh_h, 393216);
    prep_bias<<<6, 256, 0, stream>>>(b_ih, b_hh, bias2, 1536);

    gemm_xproj<false><<<dim3(512, 6), 256, 0, stream>>>(x, Wih_h, bias2, xproj);
    gru_scan_mfma<false><<<32, 512, 0, stream>>>(xproj, Whh_h, b_hh, nullptr, y1h);

    gemm_xproj<true><<<dim3(512, 6), 256, 0, stream>>>(y1h, Wih_h + 196608, bias2 + 768, xproj);
    gru_scan_mfma<true><<<32, 512, 0, stream>>>(xproj, Whh_h + 196608, b_hh + 768, out, nullptr);
}